// Round 1
// baseline (854.597 us; speedup 1.0000x reference)
//
#include <hip/hip_runtime.h>
#include <hip/hip_bf16.h>
#include <math.h>

// Problem constants (B,T,D,W,H) = (4096,1,4096,4,512)
#define B_  4096
#define D_  4096
#define W_  4
#define H_  512
#define NDW (D_*W_)   // 16384

typedef float  f32x4  __attribute__((ext_vector_type(4)));
typedef __bf16 bf16x8 __attribute__((ext_vector_type(8)));

__device__ __forceinline__ unsigned short f32_to_bf16(float f) {
    unsigned int u = __float_as_uint(f);
    u += 0x7fffu + ((u >> 16) & 1u);   // round-to-nearest-even
    return (unsigned short)(u >> 16);
}

__device__ __forceinline__ float silu_f(float v) {
    return v / (1.0f + __expf(-v));
}

// ---------------------------------------------------------------- casts ----
__global__ void cast_g_kernel(const float* __restrict__ in,
                              unsigned short* __restrict__ out, int n4) {
    int i = blockIdx.x * blockDim.x + threadIdx.x;
    if (i >= n4) return;
    float4 v = ((const float4*)in)[i];
    ushort4 o;
    o.x = f32_to_bf16(v.x); o.y = f32_to_bf16(v.y);
    o.z = f32_to_bf16(v.z); o.w = f32_to_bf16(v.w);
    ((ushort4*)out)[i] = o;
}

// in: R x C f32 (row-major) -> out: C x R bf16 (row-major)
__global__ void transpose_cast_kernel(const float* __restrict__ in,
                                      unsigned short* __restrict__ out,
                                      int R, int C) {
    __shared__ unsigned short tile[64][65];
    const int r0 = blockIdx.y * 64;
    const int c0 = blockIdx.x * 64;
    const int tx = threadIdx.x & 63;
    const int ty = threadIdx.x >> 6;  // 0..3
#pragma unroll
    for (int rr = ty; rr < 64; rr += 4)
        tile[rr][tx] = f32_to_bf16(in[(size_t)(r0 + rr) * C + c0 + tx]);
    __syncthreads();
#pragma unroll
    for (int cc = ty; cc < 64; cc += 4)
        out[(size_t)(c0 + cc) * R + r0 + tx] = tile[tx][cc];
}

// ---------------------------------------------------------------- GEMM -----
// C = A(MxK, bf16 row-major) * Bt(NxK, bf16 row-major)^T
// EPI==0: out = silu(C) as bf16 -> Hout
// EPI==1: out = C + bias[col] as f32 -> Fout
template<int EPI>
__global__ __launch_bounds__(256)
void gemm_bt(const unsigned short* __restrict__ A,
             const unsigned short* __restrict__ Bt,
             unsigned short* __restrict__ Hout,
             float* __restrict__ Fout,
             const float* __restrict__ bias,
             int M, int N, int K)
{
    __shared__ unsigned short As[128 * 64];
    __shared__ unsigned short Bs[128 * 64];

    const int tid  = threadIdx.x;
    const int wave = tid >> 6;
    const int lane = tid & 63;
    const int quad = lane >> 4;
    const int l16  = lane & 15;
    const int m0 = blockIdx.y * 128;
    const int n0 = blockIdx.x * 128;
    const int wm = (wave >> 1) * 64;   // wave's M offset in tile
    const int wn = (wave & 1) * 64;    // wave's N offset in tile

    f32x4 acc[4][4];
#pragma unroll
    for (int i = 0; i < 4; ++i)
#pragma unroll
        for (int j = 0; j < 4; ++j)
            acc[i][j] = (f32x4){0.f, 0.f, 0.f, 0.f};

    for (int k0 = 0; k0 < K; k0 += 64) {
        // stage 128x64 bf16 A-tile and B-tile: 4 rounds x 256 lanes x 16B
#pragma unroll
        for (int r = 0; r < 4; ++r) {
            const int flat  = r * 256 + tid;
            const int row   = flat >> 3;   // 0..127
            const int chunk = flat & 7;    // 0..7  (8 bf16 = 16B)
            const unsigned short* gA = A  + (size_t)(m0 + row) * K + (k0 + chunk * 8);
            const unsigned short* gB = Bt + (size_t)(n0 + row) * K + (k0 + chunk * 8);
            unsigned short* lA = As + (size_t)(r * 256 + wave * 64) * 8; // wave-uniform base
            unsigned short* lB = Bs + (size_t)(r * 256 + wave * 64) * 8;
            __builtin_amdgcn_global_load_lds(
                (const __attribute__((address_space(1))) void*)gA,
                (__attribute__((address_space(3))) void*)lA, 16, 0, 0);
            __builtin_amdgcn_global_load_lds(
                (const __attribute__((address_space(1))) void*)gB,
                (__attribute__((address_space(3))) void*)lB, 16, 0, 0);
        }
        __syncthreads();

#pragma unroll
        for (int ks = 0; ks < 2; ++ks) {
            const int kk = ks * 32 + quad * 8;
            bf16x8 af[4], bfr[4];
#pragma unroll
            for (int i = 0; i < 4; ++i) {
                af[i]  = *(const bf16x8*)(As + (wm + i * 16 + l16) * 64 + kk);
                bfr[i] = *(const bf16x8*)(Bs + (wn + i * 16 + l16) * 64 + kk);
            }
#pragma unroll
            for (int i = 0; i < 4; ++i)
#pragma unroll
                for (int j = 0; j < 4; ++j)
                    acc[i][j] = __builtin_amdgcn_mfma_f32_16x16x32_bf16(
                        af[i], bfr[j], acc[i][j], 0, 0, 0);
        }
        __syncthreads();
    }

    // Epilogue. C/D layout: col = lane&15, row = quad*4 + reg  [m89/m91]
#pragma unroll
    for (int i = 0; i < 4; ++i) {
#pragma unroll
        for (int j = 0; j < 4; ++j) {
            const int col = n0 + wn + j * 16 + l16;
#pragma unroll
            for (int r = 0; r < 4; ++r) {
                const int row = m0 + wm + i * 16 + quad * 4 + r;
                float v = acc[i][j][r];
                if (EPI == 0) {
                    Hout[(size_t)row * N + col] = f32_to_bf16(silu_f(v));
                } else {
                    Fout[(size_t)row * N + col] = v + bias[col];
                }
            }
        }
    }
}

// ---------------------------------------------------------------- conv -----
// kc region holds flat_kernels (B,D,4) f32; overwritten in-place with new_cache.
__global__ void conv_kernel(const float* __restrict__ x,
                            const float* __restrict__ cache,
                            float* __restrict__ out,
                            float* __restrict__ kc, int n) {
    int i = blockIdx.x * blockDim.x + threadIdx.x;  // i = b*D + d
    if (i >= n) return;
    float4 k4 = ((const float4*)kc)[i];
    float4 c4 = ((const float4*)cache)[i];
    float  xv = x[i];
    float4 nc;
    nc.x = c4.y; nc.y = c4.z; nc.z = c4.w; nc.w = xv;
    float s = nc.x * k4.x + nc.y * k4.y + nc.z * k4.z + nc.w * k4.w;
    out[i] = silu_f(s);
    ((float4*)kc)[i] = nc;
}

// ------------------------------------------------------------- launcher ----
extern "C" void kernel_launch(void* const* d_in, const int* in_sizes, int n_in,
                              void* d_out, int out_size, void* d_ws, size_t ws_size,
                              hipStream_t stream) {
    const float* x     = (const float*)d_in[0];
    const float* gin   = (const float*)d_in[1];
    const float* cache = (const float*)d_in[2];
    const float* w1    = (const float*)d_in[3];
    const float* w2    = (const float*)d_in[4];
    const float* b2    = (const float*)d_in[5];

    float* out    = (float*)d_out;                 // (B,1,D)
    float* ncache = out + (size_t)B_ * D_;         // (B,D,W) — also kernels scratch

    unsigned short* g_bf = (unsigned short*)d_ws;          // B*D bf16
    unsigned short* w1t  = g_bf + (size_t)B_ * D_;         // H*D bf16 (w1^T)
    unsigned short* w2t  = w1t + (size_t)H_ * D_;          // NDW*H bf16 (w2^T)
    unsigned short* h_bf = w2t + (size_t)NDW * H_;         // B*H bf16

    // 1) casts / transposes
    cast_g_kernel<<<(B_ * D_ / 4 + 255) / 256, 256, 0, stream>>>(gin, g_bf, B_ * D_ / 4);
    transpose_cast_kernel<<<dim3(H_ / 64, D_ / 64), 256, 0, stream>>>(w1, w1t, D_, H_);
    transpose_cast_kernel<<<dim3(NDW / 64, H_ / 64), 256, 0, stream>>>(w2, w2t, H_, NDW);

    // 2) h = silu(g @ w1): M=B, K=D, N=H
    gemm_bt<0><<<dim3(H_ / 128, B_ / 128), 256, 0, stream>>>(
        g_bf, w1t, h_bf, nullptr, nullptr, B_, H_, D_);

    // 3) flat_kernels = h @ w2 + b2 -> into new_cache region: M=B, K=H, N=NDW
    gemm_bt<1><<<dim3(NDW / 128, B_ / 128), 256, 0, stream>>>(
        h_bf, w2t, nullptr, ncache, b2, B_, NDW, H_);

    // 4) conv + silu + cache shift (in-place over kernels)
    conv_kernel<<<(B_ * D_ + 255) / 256, 256, 0, stream>>>(x, cache, out, ncache, B_ * D_);
}

// Round 2
// 777.672 us; speedup vs baseline: 1.0989x; 1.0989x over previous
//
#include <hip/hip_runtime.h>
#include <hip/hip_bf16.h>
#include <math.h>

// Problem constants (B,T,D,W,H) = (4096,1,4096,4,512)
#define B_  4096
#define D_  4096
#define W_  4
#define H_  512
#define NDW (D_*W_)   // 16384

typedef float  f32x4  __attribute__((ext_vector_type(4)));
typedef __bf16 bf16x8 __attribute__((ext_vector_type(8)));

__device__ __forceinline__ unsigned short f32_to_bf16(float f) {
    unsigned int u = __float_as_uint(f);
    u += 0x7fffu + ((u >> 16) & 1u);   // round-to-nearest-even
    return (unsigned short)(u >> 16);
}

__device__ __forceinline__ float silu_f(float v) {
    return v / (1.0f + __expf(-v));
}

// ---------------------------------------------------------------- casts ----
__global__ void cast_g_kernel(const float* __restrict__ in,
                              unsigned short* __restrict__ out, int n4) {
    int i = blockIdx.x * blockDim.x + threadIdx.x;
    if (i >= n4) return;
    float4 v = ((const float4*)in)[i];
    ushort4 o;
    o.x = f32_to_bf16(v.x); o.y = f32_to_bf16(v.y);
    o.z = f32_to_bf16(v.z); o.w = f32_to_bf16(v.w);
    ((ushort4*)out)[i] = o;
}

// in: R x C f32 (row-major) -> out: C x R bf16 (row-major)
__global__ void transpose_cast_kernel(const float* __restrict__ in,
                                      unsigned short* __restrict__ out,
                                      int R, int C) {
    __shared__ unsigned short tile[64][65];
    const int r0 = blockIdx.y * 64;
    const int c0 = blockIdx.x * 64;
    const int tx = threadIdx.x & 63;
    const int ty = threadIdx.x >> 6;  // 0..3
#pragma unroll
    for (int rr = ty; rr < 64; rr += 4)
        tile[rr][tx] = f32_to_bf16(in[(size_t)(r0 + rr) * C + c0 + tx]);
    __syncthreads();
#pragma unroll
    for (int cc = ty; cc < 64; cc += 4)
        out[(size_t)(c0 + cc) * R + r0 + tx] = tile[tx][cc];
}

// ---------------------------------------------------------------- GEMM1 ----
// h = silu(g @ w1) -> bf16.  BM=64, BN=128 (grid 4x64 = 256 blocks so all
// 256 CUs get work; 128x128 tiles gave only 128 blocks).
__global__ __launch_bounds__(256)
void gemm1_silu(const unsigned short* __restrict__ A,
                const unsigned short* __restrict__ Bt,
                unsigned short* __restrict__ Hout,
                int M, int N, int K)
{
    __shared__ unsigned short As[64 * 64];
    __shared__ unsigned short Bs[128 * 64];

    const int tid  = threadIdx.x;
    const int wave = tid >> 6;
    const int lane = tid & 63;
    const int quad = lane >> 4;
    const int l16  = lane & 15;
    const int m0 = blockIdx.y * 64;
    const int n0 = blockIdx.x * 128;
    const int wm = (wave >> 1) * 32;   // wave: 32 rows
    const int wn = (wave & 1) * 64;    // wave: 64 cols

    f32x4 acc[2][4];
#pragma unroll
    for (int i = 0; i < 2; ++i)
#pragma unroll
        for (int j = 0; j < 4; ++j)
            acc[i][j] = (f32x4){0.f, 0.f, 0.f, 0.f};

    for (int k0 = 0; k0 < K; k0 += 64) {
#pragma unroll
        for (int r = 0; r < 2; ++r) {   // A: 64x64 bf16 = 8KB = 2 rounds
            const int flat  = r * 256 + tid;
            const int row   = flat >> 3;
            const int chunk = flat & 7;
            const unsigned short* gA = A + (size_t)(m0 + row) * K + (k0 + chunk * 8);
            unsigned short* lA = As + (size_t)(r * 256 + wave * 64) * 8;
            __builtin_amdgcn_global_load_lds(
                (const __attribute__((address_space(1))) void*)gA,
                (__attribute__((address_space(3))) void*)lA, 16, 0, 0);
        }
#pragma unroll
        for (int r = 0; r < 4; ++r) {   // B: 128x64 bf16 = 16KB = 4 rounds
            const int flat  = r * 256 + tid;
            const int row   = flat >> 3;
            const int chunk = flat & 7;
            const unsigned short* gB = Bt + (size_t)(n0 + row) * K + (k0 + chunk * 8);
            unsigned short* lB = Bs + (size_t)(r * 256 + wave * 64) * 8;
            __builtin_amdgcn_global_load_lds(
                (const __attribute__((address_space(1))) void*)gB,
                (__attribute__((address_space(3))) void*)lB, 16, 0, 0);
        }
        __syncthreads();

#pragma unroll
        for (int ks = 0; ks < 2; ++ks) {
            const int kk = ks * 32 + quad * 8;
            bf16x8 af[2], bfr[4];
#pragma unroll
            for (int i = 0; i < 2; ++i)
                af[i]  = *(const bf16x8*)(As + (wm + i * 16 + l16) * 64 + kk);
#pragma unroll
            for (int j = 0; j < 4; ++j)
                bfr[j] = *(const bf16x8*)(Bs + (wn + j * 16 + l16) * 64 + kk);
#pragma unroll
            for (int i = 0; i < 2; ++i)
#pragma unroll
                for (int j = 0; j < 4; ++j)
                    acc[i][j] = __builtin_amdgcn_mfma_f32_16x16x32_bf16(
                        af[i], bfr[j], acc[i][j], 0, 0, 0);
        }
        __syncthreads();
    }

    // C/D layout: col = lane&15, row = quad*4 + reg  [m89/m91]
#pragma unroll
    for (int i = 0; i < 2; ++i)
#pragma unroll
        for (int j = 0; j < 4; ++j) {
            const int col = n0 + wn + j * 16 + l16;
#pragma unroll
            for (int r = 0; r < 4; ++r) {
                const int row = m0 + wm + i * 16 + quad * 4 + r;
                Hout[(size_t)row * N + col] = f32_to_bf16(silu_f(acc[i][j][r]));
            }
        }
}

// ------------------------------------------------- GEMM2 + conv (fused) ----
// flat_kernels tile = h @ w2 + b2 computed in AGPRs, round-tripped through
// LDS (two 128x64 f32 halves, stride 68 => only 2-way bank aliasing, free),
// then consumed immediately: out = silu(dot(new_cache, k)), new_cache
// written directly. flat_kernels never touches HBM (-536 MB round trip).
__global__ __launch_bounds__(256)
void gemm2_conv(const unsigned short* __restrict__ A,   // h_bf  (B_ x H_)
                const unsigned short* __restrict__ Bt,  // w2t   (NDW x H_)
                const float* __restrict__ bias,
                const float* __restrict__ x,
                const float* __restrict__ cache,
                float* __restrict__ out,
                float* __restrict__ ncache)
{
    // 34816 B: K-loop uses first 32KB as As(16K)+Bs(16K); epilogue reuses
    // the whole thing as Cs = float[128][68].
    __shared__ __align__(16) unsigned short smem[128 * 68 * 2];
    unsigned short* As = smem;                 // 128x64 bf16
    unsigned short* Bs = smem + 128 * 64;      // 128x64 bf16
    float* Cs = (float*)smem;                  // 128x68 f32

    const int tid  = threadIdx.x;
    const int wave = tid >> 6;
    const int lane = tid & 63;
    const int quad = lane >> 4;
    const int l16  = lane & 15;
    const int m0 = blockIdx.y * 128;
    const int n0 = blockIdx.x * 128;
    const int wm = (wave >> 1) * 64;
    const int wn = (wave & 1) * 64;
    const int K = H_;

    f32x4 acc[4][4];
#pragma unroll
    for (int i = 0; i < 4; ++i)
#pragma unroll
        for (int j = 0; j < 4; ++j)
            acc[i][j] = (f32x4){0.f, 0.f, 0.f, 0.f};

    for (int k0 = 0; k0 < K; k0 += 64) {
#pragma unroll
        for (int r = 0; r < 4; ++r) {
            const int flat  = r * 256 + tid;
            const int row   = flat >> 3;
            const int chunk = flat & 7;
            const unsigned short* gA = A  + (size_t)(m0 + row) * K + (k0 + chunk * 8);
            const unsigned short* gB = Bt + (size_t)(n0 + row) * K + (k0 + chunk * 8);
            unsigned short* lA = As + (size_t)(r * 256 + wave * 64) * 8;
            unsigned short* lB = Bs + (size_t)(r * 256 + wave * 64) * 8;
            __builtin_amdgcn_global_load_lds(
                (const __attribute__((address_space(1))) void*)gA,
                (__attribute__((address_space(3))) void*)lA, 16, 0, 0);
            __builtin_amdgcn_global_load_lds(
                (const __attribute__((address_space(1))) void*)gB,
                (__attribute__((address_space(3))) void*)lB, 16, 0, 0);
        }
        __syncthreads();

#pragma unroll
        for (int ks = 0; ks < 2; ++ks) {
            const int kk = ks * 32 + quad * 8;
            bf16x8 af[4], bfr[4];
#pragma unroll
            for (int i = 0; i < 4; ++i) {
                af[i]  = *(const bf16x8*)(As + (wm + i * 16 + l16) * 64 + kk);
                bfr[i] = *(const bf16x8*)(Bs + (wn + i * 16 + l16) * 64 + kk);
            }
#pragma unroll
            for (int i = 0; i < 4; ++i)
#pragma unroll
                for (int j = 0; j < 4; ++j)
                    acc[i][j] = __builtin_amdgcn_mfma_f32_16x16x32_bf16(
                        af[i], bfr[j], acc[i][j], 0, 0, 0);
        }
        __syncthreads();
    }
    // after the final barrier all waves are done reading As/Bs -> reuse as Cs

#pragma unroll
    for (int h = 0; h < 2; ++h) {
        // waves owning this column-half spill acc (+bias) to LDS
        if ((wave & 1) == h) {
#pragma unroll
            for (int i = 0; i < 4; ++i)
#pragma unroll
                for (int j = 0; j < 4; ++j) {
                    const int lc = j * 16 + l16;
                    const float bv = bias[n0 + h * 64 + lc];
#pragma unroll
                    for (int r = 0; r < 4; ++r) {
                        const int lr = wm + i * 16 + quad * 4 + r;
                        Cs[lr * 68 + lc] = acc[i][j][r] + bv;
                    }
                }
        }
        __syncthreads();

        // conv over this half: 128 rows x 16 d-values
        const int dp    = tid & 15;          // d' within half
        const int rbase = tid >> 4;          // 0..15
        const int d     = (n0 >> 2) + h * 16 + dp;
#pragma unroll
        for (int rr = 0; rr < 8; ++rr) {
            const int br = rr * 16 + rbase;                 // 0..127
            const size_t gi = (size_t)(m0 + br) * D_ + d;   // (b,d) flat
            f32x4 k4 = *(const f32x4*)(Cs + br * 68 + dp * 4);
            f32x4 c4 = ((const f32x4*)cache)[gi];
            float xv = x[gi];
            f32x4 nc = { c4.y, c4.z, c4.w, xv };
            float s = nc.x * k4.x + nc.y * k4.y + nc.z * k4.z + nc.w * k4.w;
            out[gi] = silu_f(s);
            ((f32x4*)ncache)[gi] = nc;
        }
        __syncthreads();   // before next half overwrites Cs
    }
}

// ------------------------------------------------------------- launcher ----
extern "C" void kernel_launch(void* const* d_in, const int* in_sizes, int n_in,
                              void* d_out, int out_size, void* d_ws, size_t ws_size,
                              hipStream_t stream) {
    const float* x     = (const float*)d_in[0];
    const float* gin   = (const float*)d_in[1];
    const float* cache = (const float*)d_in[2];
    const float* w1    = (const float*)d_in[3];
    const float* w2    = (const float*)d_in[4];
    const float* b2    = (const float*)d_in[5];

    float* out    = (float*)d_out;                 // (B,1,D)
    float* ncache = out + (size_t)B_ * D_;         // (B,D,W)

    unsigned short* g_bf = (unsigned short*)d_ws;          // B*D bf16
    unsigned short* w1t  = g_bf + (size_t)B_ * D_;         // H*D bf16 (w1^T)
    unsigned short* w2t  = w1t + (size_t)H_ * D_;          // NDW*H bf16 (w2^T)
    unsigned short* h_bf = w2t + (size_t)NDW * H_;         // B*H bf16

    // 1) casts / transposes
    cast_g_kernel<<<(B_ * D_ / 4 + 255) / 256, 256, 0, stream>>>(gin, g_bf, B_ * D_ / 4);
    transpose_cast_kernel<<<dim3(H_ / 64, D_ / 64), 256, 0, stream>>>(w1, w1t, D_, H_);
    transpose_cast_kernel<<<dim3(NDW / 64, H_ / 64), 256, 0, stream>>>(w2, w2t, H_, NDW);

    // 2) h = silu(g @ w1): M=B, K=D, N=H  (256 blocks)
    gemm1_silu<<<dim3(H_ / 128, B_ / 64), 256, 0, stream>>>(
        g_bf, w1t, h_bf, B_, H_, D_);

    // 3) fused: flat_kernels tile (h @ w2 + b2) -> conv -> out + new_cache
    gemm2_conv<<<dim3(NDW / 128, B_ / 128), 256, 0, stream>>>(
        h_bf, w2t, b2, x, cache, out, ncache);
}